// Round 9
// baseline (86.199 us; speedup 1.0000x reference)
//
#include <hip/hip_runtime.h>
#include <stdint.h>

// R9 = R8 + measurement: rgc_main dispatched 4x (idempotent) to size T_main via
// slope: T_main = (bench - 64.8)/3. R8 post-mortem: two perf theories falsified,
// kernel counters invisible (fill dispatches own top-5) -> measure before editing.
//
// Structure (R6/R8-verified): gathered GEMM, pre-pass converts R->bf16 + padded
// W^T[16][160]; main reads MFMA fragments direct from global, no LDS/barrier.

#define NOBJ 32
#define NG   4960
#define NF   16
#define ND   16
#define KP   160
#define RELEMS (32 * NOBJ * NOBJ * ND)  // 524288

typedef __bf16 bf16x8 __attribute__((ext_vector_type(8)));
typedef float  f32x4  __attribute__((ext_vector_type(4)));

__device__ __forceinline__ unsigned f2bf1(float x) {
    unsigned u = __float_as_uint(x);
    return (u + 0x7fffu + ((u >> 16) & 1u)) >> 16;   // RNE; inputs finite
}
__device__ __forceinline__ unsigned packbf(float lo, float hi) {
    return f2bf1(lo) | (f2bf1(hi) << 16);
}

__device__ __forceinline__ int C3i(int x) { return (x * (x - 1) * (x - 2)) / 6; } // x<=34
__device__ __forceinline__ int C2i(int x) { return (x * (x - 1)) >> 1; }

__device__ __forceinline__ void unrank3_cf(int g, int& t0, int& t1, int& t2) {
    const int T = 4960 - g;                                  // [1,4960]
    int x = (int)cbrtf(6.0f * (float)T) + 1;
    x += (C3i(x) < T);
    x += (C3i(x) < T);
    x -= (C3i(x - 1) >= T);
    x -= (C3i(x - 1) >= T);
    t0 = 32 - x;
    const int rem2 = C3i(x) - T;
    const int T2   = C2i(x - 1) - rem2;
    int y = (int)(sqrtf(2.0f * (float)T2) + 0.5f);
    y += (C2i(y) < T2);
    y += (C2i(y) < T2);
    y -= (C2i(y - 1) >= T2);
    y -= (C2i(y - 1) >= T2);
    t1 = 32 - y;
    t2 = t1 + 1 + (C2i(y) - T2);
}

__global__ __launch_bounds__(256) void rgc_pre(
    const float* __restrict__ R, const float* __restrict__ Fw,
    unsigned short* __restrict__ Rbf, unsigned short* __restrict__ Wpad)
{
    const int tid = threadIdx.x;
    if (blockIdx.x < 256) {
        const int e = (blockIdx.x * 256 + tid) * 8;
        const float4* p = (const float4*)(R + e);
        const float4 v0 = p[0], v1 = p[1];
        uint4 o;
        o.x = packbf(v0.x, v0.y); o.y = packbf(v0.z, v0.w);
        o.z = packbf(v1.x, v1.y); o.w = packbf(v1.z, v1.w);
        *(uint4*)(Rbf + e) = o;
    } else {
        for (int e = tid * 8; e < NF * KP; e += 256 * 8) {   // 320 slots / 256 thr
            const int f = e / KP, k0 = e % KP;
            uint4 o = make_uint4(0u, 0u, 0u, 0u);
            if (k0 < 144) {
                const float4* p = (const float4*)(Fw + f * 144 + k0);
                const float4 v0 = p[0], v1 = p[1];
                o.x = packbf(v0.x, v0.y); o.y = packbf(v0.z, v0.w);
                o.z = packbf(v1.x, v1.y); o.w = packbf(v1.z, v1.w);
            }
            *(uint4*)(Wpad + e) = o;
        }
    }
}

__global__ __launch_bounds__(256) void rgc_main(
    const unsigned short* __restrict__ Rbf,   // bf16 bits, (32,32,32,16)
    const unsigned short* __restrict__ Wpad,  // bf16 bits, (16,160) zero-padded
    float* __restrict__ out)                  // (32,4960,16)
{
    const int tid  = threadIdx.x;
    const int wave = tid >> 6;
    const int lane = tid & 63;
    const int l15  = lane & 15;
    const int quad = lane >> 4;
    const int b0   = blockIdx.y * 2;
    const int gw   = blockIdx.x * 64 + wave * 16;

    const int g = min(gw + l15, NG - 1);
    int t0, t1, t2;
    unrank3_cf(g, t0, t1, t2);
    const int t[3] = {t0, t1, t2};

    int rowoff[9];
#pragma unroll
    for (int ij = 0; ij < 9; ++ij) {
        const int i = ij / 3, j = ij % 3;
        rowoff[ij] = (t[i] * NOBJ + t[j]) * ND;
    }

    const int hi = quad >> 1;
    const int d0 = (quad & 1) * 8;
    int ro[5];
    ro[0] = hi ? rowoff[1] : rowoff[0];
    ro[1] = hi ? rowoff[3] : rowoff[2];
    ro[2] = hi ? rowoff[5] : rowoff[4];
    ro[3] = hi ? rowoff[7] : rowoff[6];
    ro[4] = rowoff[8];

    const unsigned short* wbase = Wpad + l15 * KP + quad * 8;
    bf16x8 wf[5];
#pragma unroll
    for (int s = 0; s < 5; ++s) wf[s] = *(const bf16x8*)(wbase + s * 32);

    const int gbase = gw + quad * 4;
#pragma unroll
    for (int bb = 0; bb < 2; ++bb) {
        const int b = b0 + bb;
        const unsigned short* Rb = Rbf + (size_t)b * (NOBJ * NOBJ * ND);
        f32x4 acc = {0.f, 0.f, 0.f, 0.f};
#pragma unroll
        for (int s = 0; s < 5; ++s) {
            const bf16x8 a = *(const bf16x8*)(Rb + ro[s] + d0);
            acc = __builtin_amdgcn_mfma_f32_16x16x32_bf16(a, wf[s], acc, 0, 0, 0);
        }
#pragma unroll
        for (int r = 0; r < 4; ++r) {
            const int gg = gbase + r;
            if (gg < NG) out[((size_t)b * NG + gg) * NF + l15] = acc[r];
        }
    }
}

extern "C" void kernel_launch(void* const* d_in, const int* in_sizes, int n_in,
                              void* d_out, int out_size, void* d_ws, size_t ws_size,
                              hipStream_t stream) {
    const float* R  = (const float*)d_in[0];
    const float* Fw = (const float*)d_in[1];
    if (n_in >= 2 && in_sizes[0] == NF * 9 * ND) { R = (const float*)d_in[1]; Fw = (const float*)d_in[0]; }
    float* out = (float*)d_out;

    unsigned short* Rbf  = (unsigned short*)d_ws;                       // 1 MB
    unsigned short* Wpad = (unsigned short*)((char*)d_ws + RELEMS * 2); // 5 KB

    rgc_pre<<<dim3(257, 1), dim3(256, 1, 1), 0, stream>>>(R, Fw, Rbf, Wpad);
    dim3 grid((NG + 63) / 64, 16);   // 78 x 16 blocks, 2 batches per block
    // 4x idempotent dispatches: slope probe. T_main = (bench - R8_bench)/3.
    rgc_main<<<grid, dim3(256, 1, 1), 0, stream>>>(Rbf, Wpad, out);
    rgc_main<<<grid, dim3(256, 1, 1), 0, stream>>>(Rbf, Wpad, out);
    rgc_main<<<grid, dim3(256, 1, 1), 0, stream>>>(Rbf, Wpad, out);
    rgc_main<<<grid, dim3(256, 1, 1), 0, stream>>>(Rbf, Wpad, out);
}

// Round 10
// 67.262 us; speedup vs baseline: 1.2815x; 1.2815x over previous
//
#include <hip/hip_runtime.h>
#include <stdint.h>

// R10: single fused dispatch. R9 slope probe: main ≈ 7.1 µs, pre-pass + dispatch
// gap ≈ 9 µs of the ~16 µs kernel residual (harness floor ≈ 48.5 µs: 268 MB d_ws
// poison fill at 6.4 TB/s is inside the timed region). So: kill the pre-pass.
// Fragments are packed in-register from direct fp32 loads (RNE, bit-identical to
// R8's path: same rounding, same MFMA order -> absmax must stay 0.25).
//   C[b*G+g, f] = sum_k A[g,k]*W[k,f], k=ij*16+d (144 real, padded to 160).
// A frag (l15,quad,s): k = s*32+quad*8+{0..7} -> ij=2s+(quad>>1), d0=(quad&1)*8.
// s=4,quad>=2 is k>=144: W frag forced to zero in-register (A operand moot).

#define NOBJ 32
#define NG   4960
#define NF   16
#define ND   16

typedef __bf16 bf16x8 __attribute__((ext_vector_type(8)));
typedef float  f32x4  __attribute__((ext_vector_type(4)));

__device__ __forceinline__ unsigned f2bf1(float x) {
    unsigned u = __float_as_uint(x);
    return (u + 0x7fffu + ((u >> 16) & 1u)) >> 16;   // RNE; inputs finite
}
__device__ __forceinline__ unsigned packbf(float lo, float hi) {
    return f2bf1(lo) | (f2bf1(hi) << 16);
}
__device__ __forceinline__ bf16x8 pack8(float4 a, float4 b) {
    union { unsigned u[4]; bf16x8 v; } r;
    r.u[0] = packbf(a.x, a.y); r.u[1] = packbf(a.z, a.w);
    r.u[2] = packbf(b.x, b.y); r.u[3] = packbf(b.z, b.w);
    return r.v;
}

__device__ __forceinline__ int C3i(int x) { return (x * (x - 1) * (x - 2)) / 6; } // x<=34
__device__ __forceinline__ int C2i(int x) { return (x * (x - 1)) >> 1; }

// Combinatorial-number-system inversion, branchless fixups (R8-verified bit-exact).
__device__ __forceinline__ void unrank3_cf(int g, int& t0, int& t1, int& t2) {
    const int T = 4960 - g;                                  // [1,4960]
    int x = (int)cbrtf(6.0f * (float)T) + 1;
    x += (C3i(x) < T);
    x += (C3i(x) < T);
    x -= (C3i(x - 1) >= T);
    x -= (C3i(x - 1) >= T);
    t0 = 32 - x;
    const int rem2 = C3i(x) - T;
    const int T2   = C2i(x - 1) - rem2;
    int y = (int)(sqrtf(2.0f * (float)T2) + 0.5f);
    y += (C2i(y) < T2);
    y += (C2i(y) < T2);
    y -= (C2i(y - 1) >= T2);
    y -= (C2i(y - 1) >= T2);
    t1 = 32 - y;
    t2 = t1 + 1 + (C2i(y) - T2);
}

__global__ __launch_bounds__(256) void rgc_fused(
    const float* __restrict__ R,    // (32,32,32,16) fp32
    const float* __restrict__ Fw,   // (16,3,3,16)   fp32
    float* __restrict__ out)        // (32,4960,16)  fp32
{
    const int tid  = threadIdx.x;
    const int wave = tid >> 6;
    const int lane = tid & 63;
    const int l15  = lane & 15;               // A row (group) / B row (=f) / C col (=f)
    const int quad = lane >> 4;               // k-subchunk / C row-group
    const int b0   = blockIdx.y * 2;
    const int gw   = blockIdx.x * 64 + wave * 16;

    const int g = min(gw + l15, NG - 1);      // clamp; stores masked below
    int t0, t1, t2;
    unrank3_cf(g, t0, t1, t2);
    const int t[3] = {t0, t1, t2};

    int rowoff[9];
#pragma unroll
    for (int ij = 0; ij < 9; ++ij) {
        const int i = ij / 3, j = ij % 3;     // compile-time
        rowoff[ij] = (t[i] * NOBJ + t[j]) * ND;
    }

    const int hi = quad >> 1;
    const int d0 = (quad & 1) * 8;
    int ro[5];
    ro[0] = hi ? rowoff[1] : rowoff[0];
    ro[1] = hi ? rowoff[3] : rowoff[2];
    ro[2] = hi ? rowoff[5] : rowoff[4];
    ro[3] = hi ? rowoff[7] : rowoff[6];
    ro[4] = rowoff[8];                        // s=4,hi=1 -> k>=144, W frag = 0

    // W fragments in-register from fp32 (reused across b-loop).
    bf16x8 wf[5];
#pragma unroll
    for (int s = 0; s < 5; ++s) {
        // s<4: k0 = s*32+quad*8 <= 120 < 144 always valid.
        // s=4: valid iff quad<2; clamp address, zero the frag for quad>=2.
        const int ksafe = (s < 4) ? (s * 32 + quad * 8) : (128 + (quad & 1) * 8);
        const float4* wp = (const float4*)(Fw + l15 * 144 + ksafe);
        bf16x8 w = pack8(wp[0], wp[1]);
        if (s == 4 && quad >= 2) w = (bf16x8)(__bf16)0.0f;
        wf[s] = w;
    }

    const int gbase = gw + quad * 4;
#pragma unroll
    for (int bb = 0; bb < 2; ++bb) {
        const int b = b0 + bb;
        const float* Rb = R + (size_t)b * (NOBJ * NOBJ * ND);
        f32x4 acc = {0.f, 0.f, 0.f, 0.f};
#pragma unroll
        for (int s = 0; s < 5; ++s) {
            const float4* ap = (const float4*)(Rb + ro[s] + d0);  // 32B-aligned
            const bf16x8 a = pack8(ap[0], ap[1]);                 // L1/L2-resident
            acc = __builtin_amdgcn_mfma_f32_16x16x32_bf16(a, wf[s], acc, 0, 0, 0);
        }
        // C[row=quad*4+r][col=l15] -> out[b][gbase+r][f=l15]
#pragma unroll
        for (int r = 0; r < 4; ++r) {
            const int gg = gbase + r;
            if (gg < NG) out[((size_t)b * NG + gg) * NF + l15] = acc[r];
        }
    }
}

extern "C" void kernel_launch(void* const* d_in, const int* in_sizes, int n_in,
                              void* d_out, int out_size, void* d_ws, size_t ws_size,
                              hipStream_t stream) {
    const float* R  = (const float*)d_in[0];
    const float* Fw = (const float*)d_in[1];
    if (n_in >= 2 && in_sizes[0] == NF * 9 * ND) { R = (const float*)d_in[1]; Fw = (const float*)d_in[0]; }
    float* out = (float*)d_out;
    dim3 grid((NG + 63) / 64, 16);   // 78 x 16 blocks, 2 batches per block, 1 dispatch
    rgc_fused<<<grid, dim3(256, 1, 1), 0, stream>>>(R, Fw, out);
}

// Round 11
// 67.251 us; speedup vs baseline: 1.2818x; 1.0002x over previous
//
#include <hip/hip_runtime.h>
#include <stdint.h>

// R11: single fused dispatch + LDS-staged gather.
// R10 lesson: scattered A-gather is THE pipe; fp32 gather (64KB slice, L1 thrash)
// tripled kernel time (19.1 vs 7.1 µs). Fix: per block, stream the fp32 b-slice
// COALESCED (64B/line efficient), pack to 32KB bf16 LDS, A-frags via ds_read_b128.
//   C[b*G+g, f] = sum_k A[g,k]*W[k,f], k=ij*16+d (144 real, padded to 160).
// A frag (l15,quad,s): k=s*32+quad*8+{0..7} -> ij=2s+(quad>>1), d0=(quad&1)*8.
// s=4,quad>=2 is k>=144: W frag zeroed in-register. RNE pack + MFMA order identical
// to R8/R10 -> absmax must stay exactly 0.25.

#define NOBJ 32
#define NG   4960
#define NF   16
#define ND   16
#define SLICE (NOBJ * NOBJ * ND)   // 16384 elems per b

typedef __bf16 bf16x8 __attribute__((ext_vector_type(8)));
typedef float  f32x4  __attribute__((ext_vector_type(4)));

__device__ __forceinline__ unsigned f2bf1(float x) {
    unsigned u = __float_as_uint(x);
    return (u + 0x7fffu + ((u >> 16) & 1u)) >> 16;   // RNE; inputs finite
}
__device__ __forceinline__ unsigned packbf(float lo, float hi) {
    return f2bf1(lo) | (f2bf1(hi) << 16);
}
__device__ __forceinline__ bf16x8 pack8(float4 a, float4 b) {
    union { unsigned u[4]; bf16x8 v; } r;
    r.u[0] = packbf(a.x, a.y); r.u[1] = packbf(a.z, a.w);
    r.u[2] = packbf(b.x, b.y); r.u[3] = packbf(b.z, b.w);
    return r.v;
}

__device__ __forceinline__ int C3i(int x) { return (x * (x - 1) * (x - 2)) / 6; } // x<=34
__device__ __forceinline__ int C2i(int x) { return (x * (x - 1)) >> 1; }

// Combinatorial-number-system inversion, branchless fixups (R8-verified bit-exact).
__device__ __forceinline__ void unrank3_cf(int g, int& t0, int& t1, int& t2) {
    const int T = 4960 - g;                                  // [1,4960]
    int x = (int)cbrtf(6.0f * (float)T) + 1;
    x += (C3i(x) < T);
    x += (C3i(x) < T);
    x -= (C3i(x - 1) >= T);
    x -= (C3i(x - 1) >= T);
    t0 = 32 - x;
    const int rem2 = C3i(x) - T;
    const int T2   = C2i(x - 1) - rem2;
    int y = (int)(sqrtf(2.0f * (float)T2) + 0.5f);
    y += (C2i(y) < T2);
    y += (C2i(y) < T2);
    y -= (C2i(y - 1) >= T2);
    y -= (C2i(y - 1) >= T2);
    t1 = 32 - y;
    t2 = t1 + 1 + (C2i(y) - T2);
}

__global__ __launch_bounds__(256) void rgc_fused(
    const float* __restrict__ R,    // (32,32,32,16) fp32
    const float* __restrict__ Fw,   // (16,3,3,16)   fp32
    float* __restrict__ out)        // (32,4960,16)  fp32
{
    __shared__ unsigned short sA[SLICE];      // bf16 b-slice, row=(ti*32+tj), 32B rows

    const int tid  = threadIdx.x;
    const int wave = tid >> 6;
    const int lane = tid & 63;
    const int l15  = lane & 15;               // A row (group) / B row (=f) / C col (=f)
    const int quad = lane >> 4;               // k-subchunk / C row-group
    const int b    = blockIdx.y;
    const int g0   = blockIdx.x * 128;
    const int ngt  = min(8, (NG >> 4) - blockIdx.x * 8);   // gtiles in this block

    // ---- stage: coalesced fp32 stream -> bf16 LDS (64KB -> 32KB) ----
    const float* Rb = R + (size_t)b * SLICE;
#pragma unroll
    for (int k = 0; k < 8; ++k) {
        const int e = (tid + k * 256) * 8;                 // covers 16384 exactly
        const float4 p0 = *(const float4*)(Rb + e);
        const float4 p1 = *(const float4*)(Rb + e + 4);
        union { unsigned u[4]; uint4 v; } r;
        r.u[0] = packbf(p0.x, p0.y); r.u[1] = packbf(p0.z, p0.w);
        r.u[2] = packbf(p1.x, p1.y); r.u[3] = packbf(p1.z, p1.w);
        *(uint4*)&sA[e] = r.v;
    }

    // ---- W fragments in-register from fp32 (hoisted; reused across tiles) ----
    bf16x8 wf[5];
#pragma unroll
    for (int s = 0; s < 5; ++s) {
        const int ksafe = (s < 4) ? (s * 32 + quad * 8) : (128 + (quad & 1) * 8);
        const float4* wp = (const float4*)(Fw + l15 * 144 + ksafe);
        bf16x8 w = pack8(wp[0], wp[1]);
        if (s == 4 && quad >= 2) w = (bf16x8)(__bf16)0.0f;  // k>=144 pad
        wf[s] = w;
    }

    __syncthreads();   // only barrier

    // ---- compute: wave handles gtiles {wave, wave+4} ----
    const int hi = quad >> 1;
    const int d0 = (quad & 1) * 8;

    for (int gt = wave; gt < ngt; gt += 4) {
        const int g = g0 + gt * 16 + l15;     // always < NG (4960 = 16*310)
        int t0, t1, t2;
        unrank3_cf(g, t0, t1, t2);
        const int t[3] = {t0, t1, t2};

        int rowoff[9];
#pragma unroll
        for (int ij = 0; ij < 9; ++ij) {
            const int i = ij / 3, j = ij % 3; // compile-time
            rowoff[ij] = (t[i] * NOBJ + t[j]) * ND;
        }
        int ro[5];
        ro[0] = hi ? rowoff[1] : rowoff[0];
        ro[1] = hi ? rowoff[3] : rowoff[2];
        ro[2] = hi ? rowoff[5] : rowoff[4];
        ro[3] = hi ? rowoff[7] : rowoff[6];
        ro[4] = rowoff[8];                    // s=4,hi=1 -> k>=144, wf[4]=0 covers it

        f32x4 acc = {0.f, 0.f, 0.f, 0.f};
#pragma unroll
        for (int s = 0; s < 5; ++s) {
            const bf16x8 a = *(const bf16x8*)&sA[ro[s] + d0];   // ds_read_b128
            acc = __builtin_amdgcn_mfma_f32_16x16x32_bf16(a, wf[s], acc, 0, 0, 0);
        }

        // C[row=quad*4+r][col=l15] -> out[b][g0+gt*16+quad*4+r][f=l15]
        const size_t obase = ((size_t)b * NG + g0 + gt * 16 + quad * 4) * NF + l15;
#pragma unroll
        for (int r = 0; r < 4; ++r) out[obase + (size_t)r * NF] = acc[r];
    }
}

extern "C" void kernel_launch(void* const* d_in, const int* in_sizes, int n_in,
                              void* d_out, int out_size, void* d_ws, size_t ws_size,
                              hipStream_t stream) {
    const float* R  = (const float*)d_in[0];
    const float* Fw = (const float*)d_in[1];
    if (n_in >= 2 && in_sizes[0] == NF * 9 * ND) { R = (const float*)d_in[1]; Fw = (const float*)d_in[0]; }
    float* out = (float*)d_out;
    dim3 grid(39, 32);   // 39 gtile-octets x 32 b = 1248 blocks, one dispatch
    rgc_fused<<<grid, dim3(256, 1, 1), 0, stream>>>(R, Fw, out);
}

// Round 12
// 64.529 us; speedup vs baseline: 1.3358x; 1.0422x over previous
//
#include <hip/hip_runtime.h>
#include <stdint.h>

// R12 = R8 (best measured, 64.8) + 4-batch-blocked main (grid 78x8).
// R10/R11 lesson: all single-dispatch fused variants pin at ~67.3 regardless of
// internal structure (3 structures within 1 µs) -> the split pre(bf16)+main
// pipeline is empirically superior; optimize main's per-wave fixed cost instead.
//   C[b*G+g, f] = sum_k A[g,k]*W[k,f], k=ij*16+d (144 real, padded to 160).
// A frag (l15,quad,s): k=s*32+quad*8+{0..7} -> ij=2s+(quad>>1), d0=(quad&1)*8.

#define NOBJ 32
#define NG   4960
#define NF   16
#define ND   16
#define KP   160
#define RELEMS (32 * NOBJ * NOBJ * ND)  // 524288

typedef __bf16 bf16x8 __attribute__((ext_vector_type(8)));
typedef float  f32x4  __attribute__((ext_vector_type(4)));

__device__ __forceinline__ unsigned f2bf1(float x) {
    unsigned u = __float_as_uint(x);
    return (u + 0x7fffu + ((u >> 16) & 1u)) >> 16;   // RNE; inputs finite
}
__device__ __forceinline__ unsigned packbf(float lo, float hi) {
    return f2bf1(lo) | (f2bf1(hi) << 16);
}

__device__ __forceinline__ int C3i(int x) { return (x * (x - 1) * (x - 2)) / 6; } // x<=34
__device__ __forceinline__ int C2i(int x) { return (x * (x - 1)) >> 1; }

// Combinatorial-number-system inversion, branchless fixups (R8-verified bit-exact).
__device__ __forceinline__ void unrank3_cf(int g, int& t0, int& t1, int& t2) {
    const int T = 4960 - g;                                  // [1,4960]
    int x = (int)cbrtf(6.0f * (float)T) + 1;
    x += (C3i(x) < T);
    x += (C3i(x) < T);
    x -= (C3i(x - 1) >= T);
    x -= (C3i(x - 1) >= T);
    t0 = 32 - x;
    const int rem2 = C3i(x) - T;
    const int T2   = C2i(x - 1) - rem2;
    int y = (int)(sqrtf(2.0f * (float)T2) + 0.5f);
    y += (C2i(y) < T2);
    y += (C2i(y) < T2);
    y -= (C2i(y - 1) >= T2);
    y -= (C2i(y - 1) >= T2);
    t1 = 32 - y;
    t2 = t1 + 1 + (C2i(y) - T2);
}

// grid 257 blocks: 0..255 convert R (8 elems/thread), block 256 builds padded W^T.
__global__ __launch_bounds__(256) void rgc_pre(
    const float* __restrict__ R, const float* __restrict__ Fw,
    unsigned short* __restrict__ Rbf, unsigned short* __restrict__ Wpad)
{
    const int tid = threadIdx.x;
    if (blockIdx.x < 256) {
        const int e = (blockIdx.x * 256 + tid) * 8;
        const float4* p = (const float4*)(R + e);
        const float4 v0 = p[0], v1 = p[1];
        uint4 o;
        o.x = packbf(v0.x, v0.y); o.y = packbf(v0.z, v0.w);
        o.z = packbf(v1.x, v1.y); o.w = packbf(v1.z, v1.w);
        *(uint4*)(Rbf + e) = o;
    } else {
        for (int e = tid * 8; e < NF * KP; e += 256 * 8) {   // 320 slots / 256 thr
            const int f = e / KP, k0 = e % KP;
            uint4 o = make_uint4(0u, 0u, 0u, 0u);
            if (k0 < 144) {
                const float4* p = (const float4*)(Fw + f * 144 + k0);
                const float4 v0 = p[0], v1 = p[1];
                o.x = packbf(v0.x, v0.y); o.y = packbf(v0.z, v0.w);
                o.z = packbf(v1.x, v1.y); o.w = packbf(v1.z, v1.w);
            }
            *(uint4*)(Wpad + e) = o;                         // Wpad[f][k], k>=144 zeroed
        }
    }
}

__global__ __launch_bounds__(256) void rgc_main(
    const unsigned short* __restrict__ Rbf,   // bf16 bits, (32,32,32,16)
    const unsigned short* __restrict__ Wpad,  // bf16 bits, (16,160) zero-padded
    float* __restrict__ out)                  // (32,4960,16)
{
    const int tid  = threadIdx.x;
    const int wave = tid >> 6;
    const int lane = tid & 63;
    const int l15  = lane & 15;               // A row (group) / B row (=f) / C col (=f)
    const int quad = lane >> 4;               // k-subchunk / C row-group
    const int b0   = blockIdx.y * 4;          // R12: 4 batches per block
    const int gw   = blockIdx.x * 64 + wave * 16;

    const int g = min(gw + l15, NG - 1);      // clamp; stores masked below
    int t0, t1, t2;
    unrank3_cf(g, t0, t1, t2);
    const int t[3] = {t0, t1, t2};

    int rowoff[9];
#pragma unroll
    for (int ij = 0; ij < 9; ++ij) {
        const int i = ij / 3, j = ij % 3;     // compile-time
        rowoff[ij] = (t[i] * NOBJ + t[j]) * ND;
    }

    const int hi = quad >> 1;
    const int d0 = (quad & 1) * 8;
    int ro[5];
    ro[0] = hi ? rowoff[1] : rowoff[0];
    ro[1] = hi ? rowoff[3] : rowoff[2];
    ro[2] = hi ? rowoff[5] : rowoff[4];
    ro[3] = hi ? rowoff[7] : rowoff[6];
    ro[4] = rowoff[8];                        // s=4,hi=1 -> k>=144: W pad is 0

    // W fragments once, reused across 4 batches (5 x 4 VGPRs)
    const unsigned short* wbase = Wpad + l15 * KP + quad * 8;
    bf16x8 wf[5];
#pragma unroll
    for (int s = 0; s < 5; ++s) wf[s] = *(const bf16x8*)(wbase + s * 32);

    const int gbase = gw + quad * 4;
#pragma unroll
    for (int bb = 0; bb < 4; ++bb) {
        const int b = b0 + bb;
        const unsigned short* Rb = Rbf + (size_t)b * (NOBJ * NOBJ * ND);
        f32x4 acc = {0.f, 0.f, 0.f, 0.f};
#pragma unroll
        for (int s = 0; s < 5; ++s) {
            const bf16x8 a = *(const bf16x8*)(Rb + ro[s] + d0);   // 16B, L2-warm
            acc = __builtin_amdgcn_mfma_f32_16x16x32_bf16(a, wf[s], acc, 0, 0, 0);
        }
        // C[row=quad*4+r][col=l15] -> out[b][gbase+r][f=l15]
#pragma unroll
        for (int r = 0; r < 4; ++r) {
            const int gg = gbase + r;
            if (gg < NG) out[((size_t)b * NG + gg) * NF + l15] = acc[r];
        }
    }
}

extern "C" void kernel_launch(void* const* d_in, const int* in_sizes, int n_in,
                              void* d_out, int out_size, void* d_ws, size_t ws_size,
                              hipStream_t stream) {
    const float* R  = (const float*)d_in[0];
    const float* Fw = (const float*)d_in[1];
    if (n_in >= 2 && in_sizes[0] == NF * 9 * ND) { R = (const float*)d_in[1]; Fw = (const float*)d_in[0]; }
    float* out = (float*)d_out;

    unsigned short* Rbf  = (unsigned short*)d_ws;                       // 1 MB
    unsigned short* Wpad = (unsigned short*)((char*)d_ws + RELEMS * 2); // 5 KB

    rgc_pre<<<dim3(257, 1), dim3(256, 1, 1), 0, stream>>>(R, Fw, Rbf, Wpad);
    dim3 grid((NG + 63) / 64, 8);    // 78 x 8 blocks, 4 batches per block
    rgc_main<<<grid, dim3(256, 1, 1), 0, stream>>>(Rbf, Wpad, out);
}